// Round 6
// baseline (252.883 us; speedup 1.0000x reference)
//
#include <hip/hip_runtime.h>

#define CCH 256
#define HH 200
#define WW 200
#define HWW (HH * WW)
#define PHB 7
#define PWB 7
#define NBINS 49
#define OUTSZ (CCH * NBINS)   // 12544 floats per roi

typedef float f4v __attribute__((ext_vector_type(4)));
typedef unsigned short us4 __attribute__((ext_vector_type(4)));

__device__ __forceinline__ unsigned short f2bf(float f) {
  unsigned u = __builtin_bit_cast(unsigned, f);
  u += 0x7fffu + ((u >> 16) & 1u);   // round-to-nearest-even
  return (unsigned short)(u >> 16);
}
__device__ __forceinline__ float bf_lo(unsigned u) {
  return __builtin_bit_cast(float, u << 16);
}
__device__ __forceinline__ float bf_hi(unsigned u) {
  return __builtin_bit_cast(float, u & 0xffff0000u);
}

// ---------------------------------------------------------------------------
// Transpose+cast (B, C, H*W) fp32 -> (B, H*W, C) bf16.
// NT loads for features (streamed once, don't churn L3); REGULAR stores for
// the ws (roi kernel re-reads it -> want it resident in L3).
// ---------------------------------------------------------------------------
__global__ __launch_bounds__(256) void transpose_kernel(
    const float* __restrict__ in, unsigned short* __restrict__ out) {
  __shared__ float tile[64][65];
  const int b  = blockIdx.z;
  const int p0 = blockIdx.x * 64;   // pixel tile (HWW = 40000 = 625*64)
  const int c0 = blockIdx.y * 64;   // channel tile
  const int t  = threadIdx.x;
  const int k  = t & 15;
  const int r0 = t >> 4;
  const float* ip = in  + (size_t)b * CCH * HWW;
  unsigned short* op = out + (size_t)b * HWW * CCH;
#pragma unroll
  for (int rr = 0; rr < 4; ++rr) {
    const int c = r0 + rr * 16;
    const f4v v = __builtin_nontemporal_load(
        (const f4v*)(ip + (size_t)(c0 + c) * HWW + p0 + 4 * k));
    tile[c][4 * k + 0] = v.x;
    tile[c][4 * k + 1] = v.y;
    tile[c][4 * k + 2] = v.z;
    tile[c][4 * k + 3] = v.w;
  }
  __syncthreads();
#pragma unroll
  for (int rr = 0; rr < 4; ++rr) {
    const int p = r0 + rr * 16;
    us4 v;
    v.x = f2bf(tile[4 * k + 0][p]);
    v.y = f2bf(tile[4 * k + 1][p]);
    v.z = f2bf(tile[4 * k + 2][p]);
    v.w = f2bf(tile[4 * k + 3][p]);
    *(us4*)(op + (size_t)(p0 + p) * CCH + c0 + 4 * k) = v;
  }
}

// ---------------------------------------------------------------------------
// RoI Align on bf16 NHWC. Grid = 2*N: block = (roi n, channel-half h).
// Lane = 2 channels (one dword = 2 bf16); 64 lanes x 2 ch = 128 channels.
// 4 waves stride over the 49 bins. LDS staging 25 KB -> 6 blocks/CU, and the
// flush is one fully-contiguous 25 KB nontemporal block write.
// ---------------------------------------------------------------------------
__global__ __launch_bounds__(256, 6) void roi_kernel(
    const unsigned short* __restrict__ feat, const float* __restrict__ rois,
    const int* __restrict__ sidx, float* __restrict__ out) {
  __shared__ float s_out[128 * NBINS];  // [c_local][bin], 25088 B
  __shared__ int   s_yi[2][14];         // y0*W, y1*W
  __shared__ int   s_xi[2][14];         // x0, x1
  __shared__ float s_ly[14], s_hy[14], s_vy[14];
  __shared__ float s_lx[14], s_hx[14], s_vx[14];

  const int n = blockIdx.x >> 1;
  const int h = blockIdx.x & 1;         // channel half: [128*h, 128*h+128)
  const int t = threadIdx.x;

  const float x1 = rois[n * 4 + 0];
  const float y1 = rois[n * 4 + 1];
  const float x2 = rois[n * 4 + 2];
  const float y2 = rois[n * 4 + 3];
  const int   bb = sidx[n];
  const float bin_w = fmaxf(x2 - x1, 1.0f) / 7.0f;
  const float bin_h = fmaxf(y2 - y1, 1.0f) / 7.0f;

  if (t < 14) {
    const float tt = ((float)t + 0.5f) * 0.5f;
    const float ys = y1 + tt * bin_h;
    s_vy[t] = (ys >= -1.0f && ys <= (float)HH) ? 1.0f : 0.0f;
    const float yc  = fminf(fmaxf(ys, 0.0f), (float)(HH - 1));
    const int   yy0 = (int)yc;
    const int   yy1 = min(yy0 + 1, HH - 1);
    const float ly  = yc - (float)yy0;
    s_yi[0][t] = yy0 * WW;
    s_yi[1][t] = yy1 * WW;
    s_ly[t] = ly;
    s_hy[t] = 1.0f - ly;
  } else if (t < 28) {
    const int   i  = t - 14;
    const float tt = ((float)i + 0.5f) * 0.5f;
    const float xs = x1 + tt * bin_w;
    s_vx[i] = (xs >= -1.0f && xs <= (float)WW) ? 1.0f : 0.0f;
    const float xc  = fminf(fmaxf(xs, 0.0f), (float)(WW - 1));
    const int   xx0 = (int)xc;
    const int   xx1 = min(xx0 + 1, WW - 1);
    const float lx  = xc - (float)xx0;
    s_xi[0][i] = xx0;
    s_xi[1][i] = xx1;
    s_lx[i] = lx;
    s_hx[i] = 1.0f - lx;
  }
  __syncthreads();

  const int lane = t & 63;       // 64 lanes x 2 ch = 128 channels (this half)
  const int wv   = t >> 6;       // wave id 0..3
  // bf16 NHWC: tap (y,x) -> 4 B at Fb + (y*W+x)*CCH
  const unsigned short* Fb = feat + (size_t)bb * HWW * CCH + 128 * h + 2 * lane;

#pragma unroll 2
  for (int bin = wv; bin < NBINS; bin += 4) {
    const int ph = bin / PWB;
    const int pw = bin - ph * PWB;
    float accx = 0.0f, accy = 0.0f;
#pragma unroll
    for (int sy = 0; sy < 2; ++sy) {
      const int   iy  = ph * 2 + sy;
      const int   yr0 = s_yi[0][iy];
      const int   yr1 = s_yi[1][iy];
      const float ly  = s_ly[iy];
      const float hy  = s_hy[iy];
      const float vy  = s_vy[iy];
#pragma unroll
      for (int sx = 0; sx < 2; ++sx) {
        const int   ix  = pw * 2 + sx;
        const int   xx0 = s_xi[0][ix];
        const int   xx1 = s_xi[1][ix];
        const float m   = vy * s_vx[ix];
        const float w00 = m * s_hx[ix] * hy;
        const float w01 = m * s_lx[ix] * hy;
        const float w10 = m * s_hx[ix] * ly;
        const float w11 = m * s_lx[ix] * ly;
        const unsigned q00 = *(const unsigned*)(Fb + (size_t)(yr0 + xx0) * CCH);
        const unsigned q01 = *(const unsigned*)(Fb + (size_t)(yr0 + xx1) * CCH);
        const unsigned q10 = *(const unsigned*)(Fb + (size_t)(yr1 + xx0) * CCH);
        const unsigned q11 = *(const unsigned*)(Fb + (size_t)(yr1 + xx1) * CCH);
        accx += w00 * bf_lo(q00) + w01 * bf_lo(q01) +
                w10 * bf_lo(q10) + w11 * bf_lo(q11);
        accy += w00 * bf_hi(q00) + w01 * bf_hi(q01) +
                w10 * bf_hi(q10) + w11 * bf_hi(q11);
      }
    }
    s_out[(2 * lane + 0) * NBINS + bin] = accx * 0.25f;
    s_out[(2 * lane + 1) * NBINS + bin] = accy * 0.25f;
  }
  __syncthreads();

  // Contiguous NT float4 flush: 128*49 floats = 1568 float4 at
  // out[n] + 128*h*49 (16B-aligned: 25088 B slab).
  const f4v* so4 = (const f4v*)s_out;
  f4v*       on4 = (f4v*)(out + (size_t)n * OUTSZ + 128 * h * NBINS);
#pragma unroll
  for (int i = t; i < (128 * NBINS) / 4; i += 256) {
    __builtin_nontemporal_store(so4[i], &on4[i]);
  }
}

// ---------------------------------------------------------------------------
// Scalar NCHW fp32 fallback (only if ws too small for the bf16 copy).
// ---------------------------------------------------------------------------
__global__ __launch_bounds__(256) void roi_kernel_nchw(
    const float* __restrict__ feat, const float* __restrict__ rois,
    const int* __restrict__ sidx, float* __restrict__ out) {
  __shared__ float s_out[OUTSZ];
  __shared__ int   s_yi[2][14];
  __shared__ int   s_xi[2][14];
  __shared__ float s_ly[14], s_hy[14], s_vy[14];
  __shared__ float s_lx[14], s_hx[14], s_vx[14];
  const int n = blockIdx.x;
  const int t = threadIdx.x;
  const float x1 = rois[n * 4 + 0], y1 = rois[n * 4 + 1];
  const float x2 = rois[n * 4 + 2], y2 = rois[n * 4 + 3];
  const int   bb = sidx[n];
  const float bin_w = fmaxf(x2 - x1, 1.0f) / 7.0f;
  const float bin_h = fmaxf(y2 - y1, 1.0f) / 7.0f;
  if (t < 14) {
    const float tt = ((float)t + 0.5f) * 0.5f;
    const float ys = y1 + tt * bin_h;
    s_vy[t] = (ys >= -1.0f && ys <= (float)HH) ? 1.0f : 0.0f;
    const float yc = fminf(fmaxf(ys, 0.0f), (float)(HH - 1));
    const int yy0 = (int)yc, yy1 = min(yy0 + 1, HH - 1);
    s_yi[0][t] = yy0 * WW; s_yi[1][t] = yy1 * WW;
    s_ly[t] = yc - (float)yy0; s_hy[t] = 1.0f - s_ly[t];
  } else if (t < 28) {
    const int i = t - 14;
    const float tt = ((float)i + 0.5f) * 0.5f;
    const float xs = x1 + tt * bin_w;
    s_vx[i] = (xs >= -1.0f && xs <= (float)WW) ? 1.0f : 0.0f;
    const float xc = fminf(fmaxf(xs, 0.0f), (float)(WW - 1));
    const int xx0 = (int)xc, xx1 = min(xx0 + 1, WW - 1);
    s_xi[0][i] = xx0; s_xi[1][i] = xx1;
    s_lx[i] = xc - (float)xx0; s_hx[i] = 1.0f - s_lx[i];
  }
  __syncthreads();
  const int c = t;
  const float* Fb = feat + ((size_t)bb * CCH + c) * HWW;
  for (int bin = 0; bin < NBINS; ++bin) {
    const int ph = bin / PWB, pw = bin - ph * PWB;
    float acc = 0.0f;
    for (int sy = 0; sy < 2; ++sy) {
      const int iy = ph * 2 + sy;
      for (int sx = 0; sx < 2; ++sx) {
        const int ix = pw * 2 + sx;
        const float m = s_vy[iy] * s_vx[ix];
        acc += m * (s_hy[iy] * (s_hx[ix] * Fb[s_yi[0][iy] + s_xi[0][ix]] +
                                s_lx[ix] * Fb[s_yi[0][iy] + s_xi[1][ix]]) +
                    s_ly[iy] * (s_hx[ix] * Fb[s_yi[1][iy] + s_xi[0][ix]] +
                                s_lx[ix] * Fb[s_yi[1][iy] + s_xi[1][ix]]));
      }
    }
    s_out[c * NBINS + bin] = acc * 0.25f;
  }
  __syncthreads();
  float* on = out + (size_t)n * OUTSZ;
  for (int i = t; i < OUTSZ; i += 256) on[i] = s_out[i];
}

extern "C" void kernel_launch(void* const* d_in, const int* in_sizes, int n_in,
                              void* d_out, int out_size, void* d_ws, size_t ws_size,
                              hipStream_t stream) {
  const float* features = (const float*)d_in[0];
  const float* rois     = (const float*)d_in[1];
  const int*   sidx     = (const int*)d_in[2];
  float*       out      = (float*)d_out;

  const int N = in_sizes[1] / 4;
  const int B = in_sizes[0] / (CCH * HWW);

  const size_t need = (size_t)B * HWW * CCH * sizeof(unsigned short);
  if (ws_size >= need) {
    unsigned short* ft = (unsigned short*)d_ws;
    dim3 tgrid(HWW / 64, CCH / 64, B);
    transpose_kernel<<<tgrid, 256, 0, stream>>>(features, ft);
    roi_kernel<<<2 * N, 256, 0, stream>>>(ft, rois, sidx, out);
  } else {
    roi_kernel_nchw<<<N, 256, 0, stream>>>(features, rois, sidx, out);
  }
}

// Round 7
// 177.724 us; speedup vs baseline: 1.4229x; 1.4229x over previous
//
#include <hip/hip_runtime.h>

#define CCH 256
#define HH 200
#define WW 200
#define HWW (HH * WW)
#define PHB 7
#define PWB 7
#define NBINS 49
#define OUTSZ (CCH * NBINS)   // 12544 floats per roi

typedef float f4v __attribute__((ext_vector_type(4)));
typedef unsigned short us4 __attribute__((ext_vector_type(4)));

__device__ __forceinline__ unsigned short f2bf(float f) {
  unsigned u = __builtin_bit_cast(unsigned, f);
  u += 0x7fffu + ((u >> 16) & 1u);   // round-to-nearest-even
  return (unsigned short)(u >> 16);
}
__device__ __forceinline__ float bf_lo(unsigned u) {
  return __builtin_bit_cast(float, u << 16);
}
__device__ __forceinline__ float bf_hi(unsigned u) {
  return __builtin_bit_cast(float, u & 0xffff0000u);
}

// ---------------------------------------------------------------------------
// Transpose+cast (B, C, H*W) fp32 -> (B, H*W, C) bf16.
// NT loads for features (streamed once, don't churn L3); REGULAR stores for
// the ws (roi kernel re-reads it -> want it resident in L2/L3).
// ---------------------------------------------------------------------------
__global__ __launch_bounds__(256) void transpose_kernel(
    const float* __restrict__ in, unsigned short* __restrict__ out) {
  __shared__ float tile[64][65];
  const int b  = blockIdx.z;
  const int p0 = blockIdx.x * 64;   // pixel tile (HWW = 40000 = 625*64)
  const int c0 = blockIdx.y * 64;   // channel tile
  const int t  = threadIdx.x;
  const int k  = t & 15;
  const int r0 = t >> 4;
  const float* ip = in  + (size_t)b * CCH * HWW;
  unsigned short* op = out + (size_t)b * HWW * CCH;
#pragma unroll
  for (int rr = 0; rr < 4; ++rr) {
    const int c = r0 + rr * 16;
    const f4v v = __builtin_nontemporal_load(
        (const f4v*)(ip + (size_t)(c0 + c) * HWW + p0 + 4 * k));
    tile[c][4 * k + 0] = v.x;
    tile[c][4 * k + 1] = v.y;
    tile[c][4 * k + 2] = v.z;
    tile[c][4 * k + 3] = v.w;
  }
  __syncthreads();
#pragma unroll
  for (int rr = 0; rr < 4; ++rr) {
    const int p = r0 + rr * 16;
    us4 v;
    v.x = f2bf(tile[4 * k + 0][p]);
    v.y = f2bf(tile[4 * k + 1][p]);
    v.z = f2bf(tile[4 * k + 2][p]);
    v.w = f2bf(tile[4 * k + 3][p]);
    *(us4*)(op + (size_t)(p0 + p) * CCH + c0 + 4 * k) = v;
  }
}

// ---------------------------------------------------------------------------
// RoI Align on bf16 NHWC. Grid = 2*N: block = (roi n, channel-half h).
// Lane = 2 channels (one dword = 2 bf16); 64 lanes x 2 ch = 128 channels.
// 4 waves stride over the 49 bins. LDS staging 25 KB -> 6 blocks/CU.
// NOTE: no min-waves arg in launch_bounds — round 6 showed forcing 6
// waves/EU squeezes VGPRs to 40 and spills to scratch (+330 MB HBM traffic).
// Natural allocation (<=84 VGPR) already permits 6 waves/EU.
// ---------------------------------------------------------------------------
__global__ __launch_bounds__(256) void roi_kernel(
    const unsigned short* __restrict__ feat, const float* __restrict__ rois,
    const int* __restrict__ sidx, float* __restrict__ out) {
  __shared__ float s_out[128 * NBINS];  // [c_local][bin], 25088 B
  __shared__ int   s_yi[2][14];         // y0*W, y1*W
  __shared__ int   s_xi[2][14];         // x0, x1
  __shared__ float s_ly[14], s_hy[14], s_vy[14];
  __shared__ float s_lx[14], s_hx[14], s_vx[14];

  const int n = blockIdx.x >> 1;
  const int h = blockIdx.x & 1;         // channel half: [128*h, 128*h+128)
  const int t = threadIdx.x;

  const float x1 = rois[n * 4 + 0];
  const float y1 = rois[n * 4 + 1];
  const float x2 = rois[n * 4 + 2];
  const float y2 = rois[n * 4 + 3];
  const int   bb = sidx[n];
  const float bin_w = fmaxf(x2 - x1, 1.0f) / 7.0f;
  const float bin_h = fmaxf(y2 - y1, 1.0f) / 7.0f;

  if (t < 14) {
    const float tt = ((float)t + 0.5f) * 0.5f;
    const float ys = y1 + tt * bin_h;
    s_vy[t] = (ys >= -1.0f && ys <= (float)HH) ? 1.0f : 0.0f;
    const float yc  = fminf(fmaxf(ys, 0.0f), (float)(HH - 1));
    const int   yy0 = (int)yc;
    const int   yy1 = min(yy0 + 1, HH - 1);
    const float ly  = yc - (float)yy0;
    s_yi[0][t] = yy0 * WW;
    s_yi[1][t] = yy1 * WW;
    s_ly[t] = ly;
    s_hy[t] = 1.0f - ly;
  } else if (t < 28) {
    const int   i  = t - 14;
    const float tt = ((float)i + 0.5f) * 0.5f;
    const float xs = x1 + tt * bin_w;
    s_vx[i] = (xs >= -1.0f && xs <= (float)WW) ? 1.0f : 0.0f;
    const float xc  = fminf(fmaxf(xs, 0.0f), (float)(WW - 1));
    const int   xx0 = (int)xc;
    const int   xx1 = min(xx0 + 1, WW - 1);
    const float lx  = xc - (float)xx0;
    s_xi[0][i] = xx0;
    s_xi[1][i] = xx1;
    s_lx[i] = lx;
    s_hx[i] = 1.0f - lx;
  }
  __syncthreads();

  const int lane = t & 63;       // 64 lanes x 2 ch = 128 channels (this half)
  const int wv   = t >> 6;       // wave id 0..3
  // bf16 NHWC: tap (y,x) -> 4 B at Fb + (y*W+x)*CCH
  const unsigned short* Fb = feat + (size_t)bb * HWW * CCH + 128 * h + 2 * lane;

#pragma unroll 2
  for (int bin = wv; bin < NBINS; bin += 4) {
    const int ph = bin / PWB;
    const int pw = bin - ph * PWB;
    float accx = 0.0f, accy = 0.0f;
#pragma unroll
    for (int sy = 0; sy < 2; ++sy) {
      const int   iy  = ph * 2 + sy;
      const int   yr0 = s_yi[0][iy];
      const int   yr1 = s_yi[1][iy];
      const float ly  = s_ly[iy];
      const float hy  = s_hy[iy];
      const float vy  = s_vy[iy];
#pragma unroll
      for (int sx = 0; sx < 2; ++sx) {
        const int   ix  = pw * 2 + sx;
        const int   xx0 = s_xi[0][ix];
        const int   xx1 = s_xi[1][ix];
        const float m   = vy * s_vx[ix];
        const float w00 = m * s_hx[ix] * hy;
        const float w01 = m * s_lx[ix] * hy;
        const float w10 = m * s_hx[ix] * ly;
        const float w11 = m * s_lx[ix] * ly;
        const unsigned q00 = *(const unsigned*)(Fb + (size_t)(yr0 + xx0) * CCH);
        const unsigned q01 = *(const unsigned*)(Fb + (size_t)(yr0 + xx1) * CCH);
        const unsigned q10 = *(const unsigned*)(Fb + (size_t)(yr1 + xx0) * CCH);
        const unsigned q11 = *(const unsigned*)(Fb + (size_t)(yr1 + xx1) * CCH);
        accx += w00 * bf_lo(q00) + w01 * bf_lo(q01) +
                w10 * bf_lo(q10) + w11 * bf_lo(q11);
        accy += w00 * bf_hi(q00) + w01 * bf_hi(q01) +
                w10 * bf_hi(q10) + w11 * bf_hi(q11);
      }
    }
    s_out[(2 * lane + 0) * NBINS + bin] = accx * 0.25f;
    s_out[(2 * lane + 1) * NBINS + bin] = accy * 0.25f;
  }
  __syncthreads();

  // Contiguous float4 flush: 128*49 floats = 1568 float4 at
  // out[n] + 128*h*49 (slab is 25088 B, 128B-aligned).
  const f4v* so4 = (const f4v*)s_out;
  f4v*       on4 = (f4v*)(out + (size_t)n * OUTSZ + 128 * h * NBINS);
  for (int i = t; i < (128 * NBINS) / 4; i += 256) on4[i] = so4[i];
}

// ---------------------------------------------------------------------------
// Scalar NCHW fp32 fallback (only if ws too small for the bf16 copy).
// ---------------------------------------------------------------------------
__global__ __launch_bounds__(256) void roi_kernel_nchw(
    const float* __restrict__ feat, const float* __restrict__ rois,
    const int* __restrict__ sidx, float* __restrict__ out) {
  __shared__ float s_out[OUTSZ];
  __shared__ int   s_yi[2][14];
  __shared__ int   s_xi[2][14];
  __shared__ float s_ly[14], s_hy[14], s_vy[14];
  __shared__ float s_lx[14], s_hx[14], s_vx[14];
  const int n = blockIdx.x;
  const int t = threadIdx.x;
  const float x1 = rois[n * 4 + 0], y1 = rois[n * 4 + 1];
  const float x2 = rois[n * 4 + 2], y2 = rois[n * 4 + 3];
  const int   bb = sidx[n];
  const float bin_w = fmaxf(x2 - x1, 1.0f) / 7.0f;
  const float bin_h = fmaxf(y2 - y1, 1.0f) / 7.0f;
  if (t < 14) {
    const float tt = ((float)t + 0.5f) * 0.5f;
    const float ys = y1 + tt * bin_h;
    s_vy[t] = (ys >= -1.0f && ys <= (float)HH) ? 1.0f : 0.0f;
    const float yc = fminf(fmaxf(ys, 0.0f), (float)(HH - 1));
    const int yy0 = (int)yc, yy1 = min(yy0 + 1, HH - 1);
    s_yi[0][t] = yy0 * WW; s_yi[1][t] = yy1 * WW;
    s_ly[t] = yc - (float)yy0; s_hy[t] = 1.0f - s_ly[t];
  } else if (t < 28) {
    const int i = t - 14;
    const float tt = ((float)i + 0.5f) * 0.5f;
    const float xs = x1 + tt * bin_w;
    s_vx[i] = (xs >= -1.0f && xs <= (float)WW) ? 1.0f : 0.0f;
    const float xc = fminf(fmaxf(xs, 0.0f), (float)(WW - 1));
    const int xx0 = (int)xc, xx1 = min(xx0 + 1, WW - 1);
    s_xi[0][i] = xx0; s_xi[1][i] = xx1;
    s_lx[i] = xc - (float)xx0; s_hx[i] = 1.0f - s_lx[i];
  }
  __syncthreads();
  const int c = t;
  const float* Fb = feat + ((size_t)bb * CCH + c) * HWW;
  for (int bin = 0; bin < NBINS; ++bin) {
    const int ph = bin / PWB, pw = bin - ph * PWB;
    float acc = 0.0f;
    for (int sy = 0; sy < 2; ++sy) {
      const int iy = ph * 2 + sy;
      for (int sx = 0; sx < 2; ++sx) {
        const int ix = pw * 2 + sx;
        const float m = s_vy[iy] * s_vx[ix];
        acc += m * (s_hy[iy] * (s_hx[ix] * Fb[s_yi[0][iy] + s_xi[0][ix]] +
                                s_lx[ix] * Fb[s_yi[0][iy] + s_xi[1][ix]]) +
                    s_ly[iy] * (s_hx[ix] * Fb[s_yi[1][iy] + s_xi[0][ix]] +
                                s_lx[ix] * Fb[s_yi[1][iy] + s_xi[1][ix]]));
      }
    }
    s_out[c * NBINS + bin] = acc * 0.25f;
  }
  __syncthreads();
  float* on = out + (size_t)n * OUTSZ;
  for (int i = t; i < OUTSZ; i += 256) on[i] = s_out[i];
}

extern "C" void kernel_launch(void* const* d_in, const int* in_sizes, int n_in,
                              void* d_out, int out_size, void* d_ws, size_t ws_size,
                              hipStream_t stream) {
  const float* features = (const float*)d_in[0];
  const float* rois     = (const float*)d_in[1];
  const int*   sidx     = (const int*)d_in[2];
  float*       out      = (float*)d_out;

  const int N = in_sizes[1] / 4;
  const int B = in_sizes[0] / (CCH * HWW);

  const size_t need = (size_t)B * HWW * CCH * sizeof(unsigned short);
  if (ws_size >= need) {
    unsigned short* ft = (unsigned short*)d_ws;
    dim3 tgrid(HWW / 64, CCH / 64, B);
    transpose_kernel<<<tgrid, 256, 0, stream>>>(features, ft);
    roi_kernel<<<2 * N, 256, 0, stream>>>(ft, rois, sidx, out);
  } else {
    roi_kernel_nchw<<<N, 256, 0, stream>>>(features, rois, sidx, out);
  }
}